// Round 14
// baseline (5725.948 us; speedup 1.0000x reference)
//
#include <hip/hip_runtime.h>
#include <hip/hip_bf16.h>
#include <stdint.h>

#define B_SZ 8192
#define T_SZ 24
#define H_SZ 1024
#define G4   4096   // 4*H

typedef __attribute__((ext_vector_type(8))) short bf16x8;
typedef __attribute__((ext_vector_type(4))) float f32x4;

// opaque LDS read: compiler cannot see the LDS dependence -> no auto vmcnt drains.
#define DSR(dst, base, imm) \
    asm volatile("ds_read_b128 %0, %1 offset:" #imm : "=v"(dst) : "v"(base))

// Gate-interleaved permutation: new row p -> old row.
__device__ __forceinline__ int perm_old(int p) {
    int gate = (p >> 4) & 3;
    int unit = ((p >> 6) << 4) | (p & 15);
    return gate * 1024 + unit;
}

__device__ __forceinline__ float fast_sigmoid(float x) {
    return 1.f / (1.f + __expf(-x));
}
__device__ __forceinline__ float fast_tanh(float x) {
    float ax = __builtin_fabsf(x);
    float e  = __expf(2.f * ax);          // inf for large ax -> r = 1
    float r  = 1.f - 2.f / (e + 1.f);
    return __builtin_copysignf(r, x);
}

// ---------------- prep kernels (run once per launch) ----------------
__global__ void k_prep_w1(const float* __restrict__ Whh1, __hip_bfloat16* __restrict__ dst) {
    int i = blockIdx.x * blockDim.x + threadIdx.x;   // over 4096*1024
    int p = i >> 10, k = i & 1023;
    dst[i] = __float2bfloat16(Whh1[(size_t)perm_old(p) * 1024 + k]);
}

__global__ void k_prep_w2(const float* __restrict__ Wih2, const float* __restrict__ Whh2,
                          __hip_bfloat16* __restrict__ dst) {
    int i = blockIdx.x * blockDim.x + threadIdx.x;   // over 4096*2048
    int p = i >> 11, k = i & 2047;
    int old = perm_old(p);
    float v = (k < 1024) ? Wih2[(size_t)old * 1024 + k] : Whh2[(size_t)old * 1024 + (k - 1024)];
    dst[i] = __float2bfloat16(v);
}

__global__ void k_prep_vec(const float* __restrict__ bih1, const float* __restrict__ bhh1,
                           const float* __restrict__ bih2, const float* __restrict__ bhh2,
                           const float* __restrict__ Wih1,
                           float* __restrict__ b1p, float* __restrict__ b2p,
                           float* __restrict__ w1p) {
    int p = blockIdx.x * blockDim.x + threadIdx.x;
    if (p >= G4) return;
    int old = perm_old(p);
    b1p[p] = bih1[old] + bhh1[old];
    b2p[p] = bih2[old] + bhh2[old];
    w1p[p] = Wih1[old];
}

__global__ void k_xT(const float* __restrict__ x, float* __restrict__ xT) {
    int i = blockIdx.x * blockDim.x + threadIdx.x;   // over B*T
    if (i >= B_SZ * T_SZ) return;
    int b = i / T_SZ, t = i % T_SZ;
    xT[t * B_SZ + b] = x[i];
}

__global__ void k_init_state(const float* __restrict__ h1_0, const float* __restrict__ c1_0,
                             const float* __restrict__ h2_0, const float* __restrict__ c2_0,
                             __hip_bfloat16* __restrict__ A2_0, __hip_bfloat16* __restrict__ A2_1,
                             float* __restrict__ c1, float* __restrict__ c2) {
    int i = blockIdx.x * blockDim.x + threadIdx.x;   // over B*H
    if (i >= B_SZ * H_SZ) return;
    int b = i >> 10, j = i & 1023;
    A2_1[(size_t)b * 2048 + j]        = __float2bfloat16(h1_0[i]);
    A2_0[(size_t)b * 2048 + 1024 + j] = __float2bfloat16(h2_0[i]);
    c1[i] = c1_0[i];
    c2[i] = c2_0[i];
}

// ---------------- fused GEMM + LSTM cell, 256x256, BARRIER-FREE flag-synced -----
// 8 waves (2M x 4N), per-wave 128x64 C, BK=64, LDS 2-buf 128 KiB. ZERO s_barrier
// in the K-loop: waves rendezvous via LDS counters, drifting up to the 2-tile
// buffer depth. Per wave per tile kt (slot s = kt&1):
//   poll prodDone[s] >= 8*((kt>>1)+1)      // all waves' stage of kt landed
//   24 DSR reads ; lgkmcnt(0) ; sched_barrier(0)
//   sig consDone[s]                        // data in regs -> slot reusable
//   64 MFMA (setprio)
//   [kt+2<NK] poll consDone[s] >= 8*((kt>>1)+1) ; stage kt+2 -> slot s ;
//             vmcnt(8) -> tile kt+1 landed ; sig prodDone[(kt+1)&1]
//   [else kt+1<NK] vmcnt(0) ; sig prodDone[(kt+1)&1]
// No forced vmcnt(0)/lgkm(0) drains at sync points; a wave's read-drain stall
// overlaps its SIMD-sibling's MFMA (2 consumer waves/SIMD).
// Deadlock-free: prod sigs gate cons polls, cons sigs gate stage polls; traced.
#define BM 256
#define BN 256
#define BK 64

template<int LAYER>
__global__ __launch_bounds__(512, 2)
void k_gemm_cell(const __hip_bfloat16* __restrict__ A, int lda,
                 const __hip_bfloat16* __restrict__ Bw, int ldb, int K,
                 const float* __restrict__ biasp, const float* __restrict__ wih1p,
                 const float* __restrict__ xT, int t,
                 float* __restrict__ c, __hip_bfloat16* __restrict__ hout) {
    __shared__ short As[2][BM][BK];   // 64 KiB
    __shared__ short Bs[2][BN][BK];   // 64 KiB
    __shared__ int   sync_f[4];       // [0],[1]=prodDone  [2],[3]=consDone
    const int tid  = threadIdx.x;
    const int lane = tid & 63;
    const int wid  = tid >> 6;        // 0..7

    // XCD slab mapping (512 blocks): xcd = bid&7 owns a 16m x 4n slab,
    // within-slab m-fastest-over-8 -> ~8m x 4n concurrent group per XCD.
    const int bid = blockIdx.x;
    const int xcd = bid & 7;
    const int i   = bid >> 3;                      // 0..63
    const int ml  = (i & 7) | ((i >> 5) << 3);     // 0..15
    const int nl  = (i >> 3) & 3;                  // 0..3
    const int m0  = ((xcd & 1) * 16 + ml) * BM;
    const int n0  = ((xcd >> 1) * 4 + nl) * BN;

    const int wm = wid >> 2;          // 0..1
    const int wn = wid & 3;           // 0..3
    const int fr = lane & 15;
    const int kg = lane >> 4;

    const __hip_bfloat16* Abase = A  + (size_t)m0 * lda;
    const __hip_bfloat16* Bbase = Bw + (size_t)n0 * ldb;

    if (tid == 0) { sync_f[0] = 0; sync_f[1] = 0; sync_f[2] = 0; sync_f[3] = 0; }
    __syncthreads();   // the ONLY block-wide barrier

    f32x4 acc[8][4];
#pragma unroll
    for (int ii = 0; ii < 8; ++ii)
#pragma unroll
        for (int j = 0; j < 4; ++j) acc[ii][j] = (f32x4)0.f;

    // ---- hoisted stage pointers (r13-validated): bump += BK per staged tile.
    const int lr8 = lane >> 3;                     // 0..7
    const int cr  = lane & 7;
    const int scol = (cr ^ lr8) << 3;              // swizzled source column (involution)
    int lr0_u1[2], lr0_u2[2], lr0_u3[2], lr0_u4[2];
#pragma unroll
    for (int j = 0; j < 2; ++j) {
        int rr0 = (wid * 2 + j) * 8;
        lr0_u1[j] = (rr0 < 64) ? rr0 : rr0 + 64;           // A rows (r%128)<64
        lr0_u2[j] = (rr0 < 64) ? rr0 + 64 : rr0 + 128;     // A rows (r%128)>=64
        lr0_u3[j] = ((rr0 >> 5) << 6) + (rr0 & 31);        // B rows (r%64)<32
        lr0_u4[j] = ((rr0 >> 5) << 6) + 32 + (rr0 & 31);   // B rows (r%64)>=32
    }
    const __hip_bfloat16* gu1[2]; const __hip_bfloat16* gu2[2];
    const __hip_bfloat16* gu3[2]; const __hip_bfloat16* gu4[2];
#pragma unroll
    for (int j = 0; j < 2; ++j) {
        gu1[j] = Abase + (size_t)(lr0_u1[j] + lr8) * lda + scol;
        gu2[j] = Abase + (size_t)(lr0_u2[j] + lr8) * lda + scol;
        gu3[j] = Bbase + (size_t)(lr0_u3[j] + lr8) * ldb + scol;
        gu4[j] = Bbase + (size_t)(lr0_u4[j] + lr8) * ldb + scol;
    }
    short* const As0p = &As[0][0][0];
    short* const Bs0p = &Bs[0][0][0];

    auto st8 = [&](const __hip_bfloat16*& gp, short* dst) {
        __builtin_amdgcn_global_load_lds(
            (const __attribute__((address_space(1))) void*)gp,
            (__attribute__((address_space(3))) void*)dst, 16, 0, 0);
        gp += BK;
    };
    // stage this wave's 1/8 of one K-tile (8 loads) into LDS slot `buf`
    auto stage_all = [&](int buf) {
#pragma unroll
        for (int j = 0; j < 2; ++j) st8(gu1[j], As0p + buf * 16384 + lr0_u1[j] * 64);
#pragma unroll
        for (int j = 0; j < 2; ++j) st8(gu2[j], As0p + buf * 16384 + lr0_u2[j] * 64);
#pragma unroll
        for (int j = 0; j < 2; ++j) st8(gu3[j], Bs0p + buf * 16384 + lr0_u3[j] * 64);
#pragma unroll
        for (int j = 0; j < 2; ++j) st8(gu4[j], Bs0p + buf * 16384 + lr0_u4[j] * 64);
    };

    auto poll = [&](int idx, int target) {
        volatile int* p = (volatile int*)&sync_f[idx];
        while (*p < target) __builtin_amdgcn_s_sleep(2);
        asm volatile("" ::: "memory");
    };
    auto sig = [&](int idx) {
        if (lane == 0) atomicAdd(&sync_f[idx], 1);
    };

    // LDS byte-offset bases for asm ds_reads
    const unsigned asb = (unsigned)(uintptr_t)(__attribute__((address_space(3))) short*)As0p;
    const unsigned bsb = (unsigned)(uintptr_t)(__attribute__((address_space(3))) short*)Bs0p;
    const unsigned aoffB = (unsigned)((wm * 128 + fr) * 64) * 2;
    const unsigned boffB = (unsigned)((wn * 64 + fr) * 64) * 2;
    const unsigned ck0B  = (unsigned)((kg ^ (fr & 7)) << 3) * 2;
    const unsigned ck1B  = (unsigned)(((4 + kg) ^ (fr & 7)) << 3) * 2;

    const int NK = K >> 6;

    bf16x8 a0[4][2], a1[4][2], b0[2][2], b1[2][2];

    // ---- prologue: stage tiles 0 and 1 (this wave's shares), signal tile 0 ----
    stage_all(0);
    stage_all(1);
    asm volatile("s_waitcnt vmcnt(8)" ::: "memory");   // tile-0's 8 loads landed
    sig(0);

    for (int kt = 0; kt < NK; ++kt) {
        const int s  = kt & 1;
        const int gt = 8 * ((kt >> 1) + 1);            // cumulative per-slot target

        poll(s, gt);                                   // tile kt fully staged

        const unsigned bo  = (unsigned)s * 32768u;
        const unsigned bA0 = asb + bo + aoffB + ck0B;
        const unsigned bA1 = asb + bo + aoffB + ck1B;
        const unsigned bB0 = bsb + bo + boffB + ck0B;
        const unsigned bB1 = bsb + bo + boffB + ck1B;

        DSR(a0[0][0], bA0, 0);     DSR(a0[0][1], bA1, 0);
        DSR(a0[1][0], bA0, 2048);  DSR(a0[1][1], bA1, 2048);
        DSR(a0[2][0], bA0, 4096);  DSR(a0[2][1], bA1, 4096);
        DSR(a0[3][0], bA0, 6144);  DSR(a0[3][1], bA1, 6144);
        DSR(b0[0][0], bB0, 0);     DSR(b0[0][1], bB1, 0);
        DSR(b0[1][0], bB0, 2048);  DSR(b0[1][1], bB1, 2048);
        DSR(b1[0][0], bB0, 4096);  DSR(b1[0][1], bB1, 4096);
        DSR(b1[1][0], bB0, 6144);  DSR(b1[1][1], bB1, 6144);
        DSR(a1[0][0], bA0, 8192);  DSR(a1[0][1], bA1, 8192);
        DSR(a1[1][0], bA0, 10240); DSR(a1[1][1], bA1, 10240);
        DSR(a1[2][0], bA0, 12288); DSR(a1[2][1], bA1, 12288);
        DSR(a1[3][0], bA0, 14336); DSR(a1[3][1], bA1, 14336);
        asm volatile("s_waitcnt lgkmcnt(0)" ::: "memory");
        __builtin_amdgcn_sched_barrier(0);             // rule #18: pin MFMA below drain
        sig(2 + s);                                    // data in regs -> slot reusable

        __builtin_amdgcn_s_setprio(1);
#pragma unroll
        for (int ks = 0; ks < 2; ++ks)
#pragma unroll
            for (int m = 0; m < 4; ++m)
#pragma unroll
                for (int n = 0; n < 2; ++n)
                    acc[m][n] = __builtin_amdgcn_mfma_f32_16x16x32_bf16(a0[m][ks], b0[n][ks], acc[m][n], 0, 0, 0);
#pragma unroll
        for (int ks = 0; ks < 2; ++ks)
#pragma unroll
            for (int m = 0; m < 4; ++m)
#pragma unroll
                for (int n = 0; n < 2; ++n)
                    acc[m][2 + n] = __builtin_amdgcn_mfma_f32_16x16x32_bf16(a0[m][ks], b1[n][ks], acc[m][2 + n], 0, 0, 0);
#pragma unroll
        for (int ks = 0; ks < 2; ++ks)
#pragma unroll
            for (int m = 0; m < 4; ++m)
#pragma unroll
                for (int n = 0; n < 2; ++n)
                    acc[4 + m][n] = __builtin_amdgcn_mfma_f32_16x16x32_bf16(a1[m][ks], b0[n][ks], acc[4 + m][n], 0, 0, 0);
#pragma unroll
        for (int ks = 0; ks < 2; ++ks)
#pragma unroll
            for (int m = 0; m < 4; ++m)
#pragma unroll
                for (int n = 0; n < 2; ++n)
                    acc[4 + m][2 + n] = __builtin_amdgcn_mfma_f32_16x16x32_bf16(a1[m][ks], b1[n][ks], acc[4 + m][2 + n], 0, 0, 0);
        __builtin_amdgcn_s_setprio(0);

        if (kt + 2 < NK) {
            poll(2 + s, gt);                           // all 8 waves consumed tile kt
            stage_all(s);                              // stage tile kt+2 into slot s
            asm volatile("s_waitcnt vmcnt(8)" ::: "memory");   // tile kt+1 landed
            sig((kt + 1) & 1);
        } else if (kt + 1 < NK) {
            asm volatile("s_waitcnt vmcnt(0)" ::: "memory");   // tail drain
            sig((kt + 1) & 1);
        }
    }

    // ---- fused cell epilogue (per-wave independent; no barrier needed) ----
    float biasv[4], xwv[4];
#pragma unroll
    for (int n = 0; n < 4; ++n) {
        int col = n0 + wn * 64 + n * 16 + fr;
        biasv[n] = biasp[col];
        if (LAYER == 1) xwv[n] = wih1p[col];
    }
    const int u = ((n0 >> 6) + wn) * 16 + fr;   // global unit index 0..1023

#pragma unroll
    for (int m = 0; m < 8; ++m) {
        int rbase = m0 + wm * 128 + m * 16 + (lane >> 4) * 4;
#pragma unroll
        for (int j = 0; j < 4; ++j) {
            int b = rbase + j;
            float gi = acc[m][0][j] + biasv[0];
            float gf = acc[m][1][j] + biasv[1];
            float gg = acc[m][2][j] + biasv[2];
            float go = acc[m][3][j] + biasv[3];
            if (LAYER == 1) {
                float xv = xT[t * B_SZ + b];
                gi += xv * xwv[0];
                gf += xv * xwv[1];
                gg += xv * xwv[2];
                go += xv * xwv[3];
            }
            float si = fast_sigmoid(gi);
            float sf = fast_sigmoid(gf);
            float so = fast_sigmoid(go);
            float tg = fast_tanh(gg);
            size_t ci = (size_t)b * H_SZ + u;
            float cn = sf * c[ci] + si * tg;
            c[ci] = cn;
            hout[(size_t)b * 2048 + u] = __float2bfloat16(so * fast_tanh(cn));
        }
    }
}

// ---------------- output projection ----------------
__global__ __launch_bounds__(256)
void k_out(const __hip_bfloat16* __restrict__ h2base, const float* __restrict__ Wout,
           const float* __restrict__ bout, float* __restrict__ out) {
    int gw   = (blockIdx.x * blockDim.x + threadIdx.x) >> 6;
    int lane = threadIdx.x & 63;
    if (gw >= B_SZ) return;
    const __hip_bfloat16* h = h2base + (size_t)gw * 2048;
    float a0 = 0.f, a1 = 0.f;
#pragma unroll
    for (int k = lane; k < 1024; k += 64) {
        float hv = __bfloat162float(h[k]);
        a0 += hv * Wout[k];
        a1 += hv * Wout[1024 + k];
    }
    for (int off = 32; off; off >>= 1) {
        a0 += __shfl_down(a0, off);
        a1 += __shfl_down(a1, off);
    }
    if (lane == 0) {
        out[gw * 2 + 0] = a0 + bout[0];
        out[gw * 2 + 1] = a1 + bout[1];
    }
}

extern "C" void kernel_launch(void* const* d_in, const int* in_sizes, int n_in,
                              void* d_out, int out_size, void* d_ws, size_t ws_size,
                              hipStream_t stream) {
    const float* x    = (const float*)d_in[0];
    const float* h1_0 = (const float*)d_in[1];
    const float* c1_0 = (const float*)d_in[2];
    const float* h2_0 = (const float*)d_in[3];
    const float* c2_0 = (const float*)d_in[4];
    const float* Wih1 = (const float*)d_in[5];
    const float* Whh1 = (const float*)d_in[6];
    const float* bih1 = (const float*)d_in[7];
    const float* bhh1 = (const float*)d_in[8];
    const float* Wih2 = (const float*)d_in[9];
    const float* Whh2 = (const float*)d_in[10];
    const float* bih2 = (const float*)d_in[11];
    const float* bhh2 = (const float*)d_in[12];
    const float* Wout = (const float*)d_in[13];
    const float* bout = (const float*)d_in[14];
    float* out = (float*)d_out;
    (void)in_sizes; (void)n_in; (void)out_size; (void)ws_size;

    uint8_t* ws = (uint8_t*)d_ws;
    size_t off = 0;
    auto alloc = [&](size_t bytes) { void* p = ws + off; off += (bytes + 255) & ~(size_t)255; return p; };
    __hip_bfloat16* A2_0  = (__hip_bfloat16*)alloc((size_t)B_SZ * 2048 * 2);
    __hip_bfloat16* A2_1  = (__hip_bfloat16*)alloc((size_t)B_SZ * 2048 * 2);
    float*          c1    = (float*)alloc((size_t)B_SZ * H_SZ * 4);
    float*          c2    = (float*)alloc((size_t)B_SZ * H_SZ * 4);
    __hip_bfloat16* Whh1p = (__hip_bfloat16*)alloc((size_t)G4 * H_SZ * 2);
    __hip_bfloat16* Wcat2p= (__hip_bfloat16*)alloc((size_t)G4 * 2048 * 2);
    float*          bias1p= (float*)alloc(G4 * 4);
    float*          bias2p= (float*)alloc(G4 * 4);
    float*          wih1p = (float*)alloc(G4 * 4);
    float*          xT    = (float*)alloc((size_t)T_SZ * B_SZ * 4);

    __hip_bfloat16* A2[2] = { A2_0, A2_1 };

    k_prep_w1<<<(G4 * H_SZ + 255) / 256, 256, 0, stream>>>(Whh1, Whh1p);
    k_prep_w2<<<(G4 * 2048 + 255) / 256, 256, 0, stream>>>(Wih2, Whh2, Wcat2p);
    k_prep_vec<<<(G4 + 255) / 256, 256, 0, stream>>>(bih1, bhh1, bih2, bhh2, Wih1,
                                                     bias1p, bias2p, wih1p);
    k_xT<<<(B_SZ * T_SZ + 255) / 256, 256, 0, stream>>>(x, xT);
    k_init_state<<<(B_SZ * H_SZ + 255) / 256, 256, 0, stream>>>(h1_0, c1_0, h2_0, c2_0,
                                                                A2_0, A2_1, c1, c2);

    const int gemm_blocks = (B_SZ / BM) * (G4 / BN);   // 512

    for (int t = 0; t < T_SZ; ++t) {
        __hip_bfloat16* Pprev = A2[(t + 1) & 1];   // P_{t-1}
        __hip_bfloat16* Pt    = A2[t & 1];         // P_t
        // layer 1: reads h1_{t-1} (Pprev first half), writes h1_t -> Pt first half
        k_gemm_cell<1><<<gemm_blocks, 512, 0, stream>>>(
            (const __hip_bfloat16*)Pprev, 2048, Whh1p, 1024, 1024,
            bias1p, wih1p, xT, t, c1, Pt);
        // layer 2: reads [h1_t | h2_{t-1}] = Pt, writes h2_t -> P_{t+1} second half
        k_gemm_cell<2><<<gemm_blocks, 512, 0, stream>>>(
            (const __hip_bfloat16*)Pt, 2048, Wcat2p, 2048, 2048,
            bias2p, nullptr, nullptr, 0, c2, A2[(t + 1) & 1] + 1024);
    }
    // final h2 is in P_24 = A2[0] second half (T=24 even)
    k_out<<<(B_SZ * 64 + 255) / 256, 256, 0, stream>>>(A2_0 + 1024, Wout, bout, out);
}

// Round 15
// 5188.005 us; speedup vs baseline: 1.1037x; 1.1037x over previous
//
#include <hip/hip_runtime.h>
#include <hip/hip_bf16.h>
#include <stdint.h>

#define B_SZ 8192
#define T_SZ 24
#define H_SZ 1024
#define G4   4096   // 4*H

typedef __attribute__((ext_vector_type(8))) short bf16x8;
typedef __attribute__((ext_vector_type(4))) float f32x4;

// opaque LDS read: compiler cannot see the LDS dependence -> no auto vmcnt drains.
#define DSR(dst, base, imm) \
    asm volatile("ds_read_b128 %0, %1 offset:" #imm : "=v"(dst) : "v"(base))

// Gate-interleaved permutation: new row p -> old row.
__device__ __forceinline__ int perm_old(int p) {
    int gate = (p >> 4) & 3;
    int unit = ((p >> 6) << 4) | (p & 15);
    return gate * 1024 + unit;
}

__device__ __forceinline__ float fast_sigmoid(float x) {
    return 1.f / (1.f + __expf(-x));
}
__device__ __forceinline__ float fast_tanh(float x) {
    float ax = __builtin_fabsf(x);
    float e  = __expf(2.f * ax);          // inf for large ax -> r = 1
    float r  = 1.f - 2.f / (e + 1.f);
    return __builtin_copysignf(r, x);
}

// ---------------- prep kernels (run once per launch) ----------------
__global__ void k_prep_w1(const float* __restrict__ Whh1, __hip_bfloat16* __restrict__ dst) {
    int i = blockIdx.x * blockDim.x + threadIdx.x;   // over 4096*1024
    int p = i >> 10, k = i & 1023;
    dst[i] = __float2bfloat16(Whh1[(size_t)perm_old(p) * 1024 + k]);
}

__global__ void k_prep_w2(const float* __restrict__ Wih2, const float* __restrict__ Whh2,
                          __hip_bfloat16* __restrict__ dst) {
    int i = blockIdx.x * blockDim.x + threadIdx.x;   // over 4096*2048
    int p = i >> 11, k = i & 2047;
    int old = perm_old(p);
    float v = (k < 1024) ? Wih2[(size_t)old * 1024 + k] : Whh2[(size_t)old * 1024 + (k - 1024)];
    dst[i] = __float2bfloat16(v);
}

__global__ void k_prep_vec(const float* __restrict__ bih1, const float* __restrict__ bhh1,
                           const float* __restrict__ bih2, const float* __restrict__ bhh2,
                           const float* __restrict__ Wih1,
                           float* __restrict__ b1p, float* __restrict__ b2p,
                           float* __restrict__ w1p) {
    int p = blockIdx.x * blockDim.x + threadIdx.x;
    if (p >= G4) return;
    int old = perm_old(p);
    b1p[p] = bih1[old] + bhh1[old];
    b2p[p] = bih2[old] + bhh2[old];
    w1p[p] = Wih1[old];
}

__global__ void k_xT(const float* __restrict__ x, float* __restrict__ xT) {
    int i = blockIdx.x * blockDim.x + threadIdx.x;   // over B*T
    if (i >= B_SZ * T_SZ) return;
    int b = i / T_SZ, t = i % T_SZ;
    xT[t * B_SZ + b] = x[i];
}

__global__ void k_init_state(const float* __restrict__ h1_0, const float* __restrict__ c1_0,
                             const float* __restrict__ h2_0, const float* __restrict__ c2_0,
                             __hip_bfloat16* __restrict__ A2_0, __hip_bfloat16* __restrict__ A2_1,
                             float* __restrict__ c1, float* __restrict__ c2) {
    int i = blockIdx.x * blockDim.x + threadIdx.x;   // over B*H
    if (i >= B_SZ * H_SZ) return;
    int b = i >> 10, j = i & 1023;
    A2_1[(size_t)b * 2048 + j]        = __float2bfloat16(h1_0[i]);
    A2_0[(size_t)b * 2048 + 1024 + j] = __float2bfloat16(h2_0[i]);
    c1[i] = c1_0[i];
    c2[i] = c2_0[i];
}

// ---------------- fused GEMM + LSTM cell, 256x256, one-phase-ahead reads ---------
// r11-validated schedule (quadrants Q1(a0,b0) Q2(a0,b1) Q3(a1,b1) Q4(a1,b0);
// reads one phase ahead; stages Q1:{u4,u2}[kt+1] Q3:{u3,u1}[kt+2]; binding
// vmcnt(4) at Q2/Q4-end) + hoisted persistent stage pointers. Best measured
// configuration of the session (round 13: 5196 us total).
#define BM 256
#define BN 256
#define BK 64

template<int LAYER>
__global__ __launch_bounds__(512, 2)
void k_gemm_cell(const __hip_bfloat16* __restrict__ A, int lda,
                 const __hip_bfloat16* __restrict__ Bw, int ldb, int K,
                 const float* __restrict__ biasp, const float* __restrict__ wih1p,
                 const float* __restrict__ xT, int t,
                 float* __restrict__ c, __hip_bfloat16* __restrict__ hout) {
    __shared__ short As[2][BM][BK];   // 64 KiB
    __shared__ short Bs[2][BN][BK];   // 64 KiB
    const int tid  = threadIdx.x;
    const int lane = tid & 63;
    const int wid  = tid >> 6;        // 0..7

    // XCD slab mapping (512 blocks): xcd = bid&7 owns a 16m x 4n slab,
    // within-slab m-fastest-over-8 -> ~8m x 4n concurrent group per XCD.
    const int bid = blockIdx.x;
    const int xcd = bid & 7;
    const int i   = bid >> 3;                      // 0..63
    const int ml  = (i & 7) | ((i >> 5) << 3);     // 0..15
    const int nl  = (i >> 3) & 3;                  // 0..3
    const int m0  = ((xcd & 1) * 16 + ml) * BM;
    const int n0  = ((xcd >> 1) * 4 + nl) * BN;

    const int wm = wid >> 2;          // 0..1
    const int wn = wid & 3;           // 0..3
    const int fr = lane & 15;
    const int kg = lane >> 4;

    const __hip_bfloat16* Abase = A  + (size_t)m0 * lda;
    const __hip_bfloat16* Bbase = Bw + (size_t)n0 * ldb;

    f32x4 acc[8][4];
#pragma unroll
    for (int ii = 0; ii < 8; ++ii)
#pragma unroll
        for (int j = 0; j < 4; ++j) acc[ii][j] = (f32x4)0.f;

    // ---- hoisted stage pointers: one per (unit, j), bump += BK per staged tile.
    // lr0 multiples of 8 => lr&7 == lane>>3; source col pre-swizzled (involution).
    const int lr8 = lane >> 3;                     // 0..7
    const int cr  = lane & 7;
    const int scol = (cr ^ lr8) << 3;              // swizzled source column
    int lr0_u1[2], lr0_u2[2], lr0_u3[2], lr0_u4[2];
#pragma unroll
    for (int j = 0; j < 2; ++j) {
        int rr0 = (wid * 2 + j) * 8;
        lr0_u1[j] = (rr0 < 64) ? rr0 : rr0 + 64;           // A rows (r%128)<64
        lr0_u2[j] = (rr0 < 64) ? rr0 + 64 : rr0 + 128;     // A rows (r%128)>=64
        lr0_u3[j] = ((rr0 >> 5) << 6) + (rr0 & 31);        // B rows (r%64)<32
        lr0_u4[j] = ((rr0 >> 5) << 6) + 32 + (rr0 & 31);   // B rows (r%64)>=32
    }
    const __hip_bfloat16* gu1[2]; const __hip_bfloat16* gu2[2];
    const __hip_bfloat16* gu3[2]; const __hip_bfloat16* gu4[2];
#pragma unroll
    for (int j = 0; j < 2; ++j) {
        gu1[j] = Abase + (size_t)(lr0_u1[j] + lr8) * lda + scol;
        gu2[j] = Abase + (size_t)(lr0_u2[j] + lr8) * lda + scol;
        gu3[j] = Bbase + (size_t)(lr0_u3[j] + lr8) * ldb + scol;
        gu4[j] = Bbase + (size_t)(lr0_u4[j] + lr8) * ldb + scol;
    }
    short* const As0p = &As[0][0][0];
    short* const Bs0p = &Bs[0][0][0];

    auto st8 = [&](const __hip_bfloat16*& gp, short* dst) {
        __builtin_amdgcn_global_load_lds(
            (const __attribute__((address_space(1))) void*)gp,
            (__attribute__((address_space(3))) void*)dst, 16, 0, 0);
        gp += BK;
    };
    auto stage_u1 = [&](int buf) {
#pragma unroll
        for (int j = 0; j < 2; ++j) st8(gu1[j], As0p + buf * 16384 + lr0_u1[j] * 64);
    };
    auto stage_u2 = [&](int buf) {
#pragma unroll
        for (int j = 0; j < 2; ++j) st8(gu2[j], As0p + buf * 16384 + lr0_u2[j] * 64);
    };
    auto stage_u3 = [&](int buf) {
#pragma unroll
        for (int j = 0; j < 2; ++j) st8(gu3[j], Bs0p + buf * 16384 + lr0_u3[j] * 64);
    };
    auto stage_u4 = [&](int buf) {
#pragma unroll
        for (int j = 0; j < 2; ++j) st8(gu4[j], Bs0p + buf * 16384 + lr0_u4[j] * 64);
    };

    // LDS byte-offset bases for asm ds_reads (AS3 pointer -> 32-bit offset)
    const unsigned asb = (unsigned)(uintptr_t)(__attribute__((address_space(3))) short*)As0p;
    const unsigned bsb = (unsigned)(uintptr_t)(__attribute__((address_space(3))) short*)Bs0p;
    const unsigned aoffB = (unsigned)((wm * 128 + fr) * 64) * 2;
    const unsigned boffB = (unsigned)((wn * 64 + fr) * 64) * 2;
    const unsigned ck0B  = (unsigned)((kg ^ (fr & 7)) << 3) * 2;
    const unsigned ck1B  = (unsigned)(((4 + kg) ^ (fr & 7)) << 3) * 2;

    const int NK = K >> 6;

    bf16x8 a0[4][2], a1[4][2], b0[2][2], b1[2][2];

    // ---- prologue: tile0 all units + {u3,u1}[1]  (12 loads/thread) ----
    stage_u1(0); stage_u3(0); stage_u2(0); stage_u4(0);
    stage_u3(1); stage_u1(1);
    asm volatile("s_waitcnt vmcnt(4)" ::: "memory");   // tile-0 landed
    __builtin_amdgcn_s_barrier();
    {   // late-read pattern for tile 0: b0[0], a0[0] from buf 0
        const unsigned bA0 = asb + aoffB + ck0B;
        const unsigned bA1 = asb + aoffB + ck1B;
        const unsigned bB0 = bsb + boffB + ck0B;
        const unsigned bB1 = bsb + boffB + ck1B;
        DSR(b0[0][0], bB0, 0);    DSR(b0[0][1], bB1, 0);
        DSR(b0[1][0], bB0, 2048); DSR(b0[1][1], bB1, 2048);
        DSR(a0[0][0], bA0, 0);    DSR(a0[0][1], bA1, 0);
        DSR(a0[1][0], bA0, 2048); DSR(a0[1][1], bA1, 2048);
        DSR(a0[2][0], bA0, 4096); DSR(a0[2][1], bA1, 4096);
        DSR(a0[3][0], bA0, 6144); DSR(a0[3][1], bA1, 6144);
    }

    for (int kt = 0; kt < NK; ++kt) {
        const int buf = kt & 1;
        const unsigned bo  = (unsigned)buf * 32768u;
        const unsigned nbo = bo ^ 32768u;
        const unsigned bA0 = asb + bo + aoffB + ck0B;
        const unsigned bA1 = asb + bo + aoffB + ck1B;
        const unsigned bB0 = bsb + bo + boffB + ck0B;
        const unsigned bB1 = bsb + bo + boffB + ck1B;
        const unsigned nA0 = asb + nbo + aoffB + ck0B;
        const unsigned nA1 = asb + nbo + aoffB + ck1B;
        const unsigned nB0 = bsb + nbo + boffB + ck0B;
        const unsigned nB1 = bsb + nbo + boffB + ck1B;

        // ---------- Q1: (mq0,nq0); issue b1[kt](4); stage {u4,u2}[kt+1] ----------
        DSR(b1[0][0], bB0, 4096); DSR(b1[0][1], bB1, 4096);
        DSR(b1[1][0], bB0, 6144); DSR(b1[1][1], bB1, 6144);
        if (kt + 1 < NK) { stage_u4(buf ^ 1); stage_u2(buf ^ 1); }
        __builtin_amdgcn_s_barrier();
        asm volatile("s_waitcnt lgkmcnt(4)" ::: "memory");   // a0,b0[kt] complete
        __builtin_amdgcn_sched_barrier(0);
        __builtin_amdgcn_s_setprio(1);
#pragma unroll
        for (int ks = 0; ks < 2; ++ks)
#pragma unroll
            for (int m = 0; m < 4; ++m)
#pragma unroll
                for (int n = 0; n < 2; ++n)
                    acc[m][n] = __builtin_amdgcn_mfma_f32_16x16x32_bf16(a0[m][ks], b0[n][ks], acc[m][n], 0, 0, 0);
        __builtin_amdgcn_s_setprio(0);
        __builtin_amdgcn_s_barrier();

        // ---------- Q2: (mq0,nq1); issue a1[kt](8) ----------
        DSR(a1[0][0], bA0, 8192);  DSR(a1[0][1], bA1, 8192);
        DSR(a1[1][0], bA0, 10240); DSR(a1[1][1], bA1, 10240);
        DSR(a1[2][0], bA0, 12288); DSR(a1[2][1], bA1, 12288);
        DSR(a1[3][0], bA0, 14336); DSR(a1[3][1], bA1, 14336);
        __builtin_amdgcn_s_barrier();
        asm volatile("s_waitcnt lgkmcnt(8)" ::: "memory");   // b1[kt] complete
        __builtin_amdgcn_sched_barrier(0);
        __builtin_amdgcn_s_setprio(1);
#pragma unroll
        for (int ks = 0; ks < 2; ++ks)
#pragma unroll
            for (int m = 0; m < 4; ++m)
#pragma unroll
                for (int n = 0; n < 2; ++n)
                    acc[m][2 + n] = __builtin_amdgcn_mfma_f32_16x16x32_bf16(a0[m][ks], b1[n][ks], acc[m][2 + n], 0, 0, 0);
        __builtin_amdgcn_s_setprio(0);
        asm volatile("s_waitcnt vmcnt(4)" ::: "memory");     // {u3,u1}[kt+1] landed
        __builtin_amdgcn_s_barrier();

        // ---------- Q3: (mq1,nq1); stage {u3,u1}[kt+2] ----------
        if (kt + 2 < NK) { stage_u3(buf); stage_u1(buf); }
        __builtin_amdgcn_s_barrier();
        asm volatile("s_waitcnt lgkmcnt(0)" ::: "memory");   // a1[kt] complete
        __builtin_amdgcn_sched_barrier(0);
        __builtin_amdgcn_s_setprio(1);
#pragma unroll
        for (int ks = 0; ks < 2; ++ks)
#pragma unroll
            for (int m = 0; m < 4; ++m)
#pragma unroll
                for (int n = 0; n < 2; ++n)
                    acc[4 + m][2 + n] = __builtin_amdgcn_mfma_f32_16x16x32_bf16(a1[m][ks], b1[n][ks], acc[4 + m][2 + n], 0, 0, 0);
        __builtin_amdgcn_s_setprio(0);
        __builtin_amdgcn_s_barrier();

        // ---------- Q4: (mq1,nq0); late-issue b0,a0[kt+1](12) after MFMA ----------
        __builtin_amdgcn_s_setprio(1);
#pragma unroll
        for (int ks = 0; ks < 2; ++ks)
#pragma unroll
            for (int m = 0; m < 4; ++m)
#pragma unroll
                for (int n = 0; n < 2; ++n)
                    acc[4 + m][n] = __builtin_amdgcn_mfma_f32_16x16x32_bf16(a1[m][ks], b0[n][ks], acc[4 + m][n], 0, 0, 0);
        __builtin_amdgcn_s_setprio(0);
        __builtin_amdgcn_sched_barrier(0);                   // pin: reads below must not hoist above MFMA
        if (kt + 1 < NK) {
            DSR(b0[0][0], nB0, 0);    DSR(b0[0][1], nB1, 0);
            DSR(b0[1][0], nB0, 2048); DSR(b0[1][1], nB1, 2048);
            DSR(a0[0][0], nA0, 0);    DSR(a0[0][1], nA1, 0);
            DSR(a0[1][0], nA0, 2048); DSR(a0[1][1], nA1, 2048);
            DSR(a0[2][0], nA0, 4096); DSR(a0[2][1], nA1, 4096);
            DSR(a0[3][0], nA0, 6144); DSR(a0[3][1], nA1, 6144);
        }
        asm volatile("s_waitcnt vmcnt(4)" ::: "memory");     // {u4,u2}[kt+1] landed
        __builtin_amdgcn_s_barrier();
    }

    // ---- fused cell epilogue ----
    float biasv[4], xwv[4];
#pragma unroll
    for (int n = 0; n < 4; ++n) {
        int col = n0 + wn * 64 + n * 16 + fr;
        biasv[n] = biasp[col];
        if (LAYER == 1) xwv[n] = wih1p[col];
    }
    const int u = ((n0 >> 6) + wn) * 16 + fr;   // global unit index 0..1023

#pragma unroll
    for (int m = 0; m < 8; ++m) {
        int rbase = m0 + wm * 128 + m * 16 + (lane >> 4) * 4;
#pragma unroll
        for (int j = 0; j < 4; ++j) {
            int b = rbase + j;
            float gi = acc[m][0][j] + biasv[0];
            float gf = acc[m][1][j] + biasv[1];
            float gg = acc[m][2][j] + biasv[2];
            float go = acc[m][3][j] + biasv[3];
            if (LAYER == 1) {
                float xv = xT[t * B_SZ + b];
                gi += xv * xwv[0];
                gf += xv * xwv[1];
                gg += xv * xwv[2];
                go += xv * xwv[3];
            }
            float si = fast_sigmoid(gi);
            float sf = fast_sigmoid(gf);
            float so = fast_sigmoid(go);
            float tg = fast_tanh(gg);
            size_t ci = (size_t)b * H_SZ + u;
            float cn = sf * c[ci] + si * tg;
            c[ci] = cn;
            hout[(size_t)b * 2048 + u] = __float2bfloat16(so * fast_tanh(cn));
        }
    }
}

// ---------------- output projection ----------------
__global__ __launch_bounds__(256)
void k_out(const __hip_bfloat16* __restrict__ h2base, const float* __restrict__ Wout,
           const float* __restrict__ bout, float* __restrict__ out) {
    int gw   = (blockIdx.x * blockDim.x + threadIdx.x) >> 6;
    int lane = threadIdx.x & 63;
    if (gw >= B_SZ) return;
    const __hip_bfloat16* h = h2base + (size_t)gw * 2048;
    float a0 = 0.f, a1 = 0.f;
#pragma unroll
    for (int k = lane; k < 1024; k += 64) {
        float hv = __bfloat162float(h[k]);
        a0 += hv * Wout[k];
        a1 += hv * Wout[1024 + k];
    }
    for (int off = 32; off; off >>= 1) {
        a0 += __shfl_down(a0, off);
        a1 += __shfl_down(a1, off);
    }
    if (lane == 0) {
        out[gw * 2 + 0] = a0 + bout[0];
        out[gw * 2 + 1] = a1 + bout[1];
    }
}

extern "C" void kernel_launch(void* const* d_in, const int* in_sizes, int n_in,
                              void* d_out, int out_size, void* d_ws, size_t ws_size,
                              hipStream_t stream) {
    const float* x    = (const float*)d_in[0];
    const float* h1_0 = (const float*)d_in[1];
    const float* c1_0 = (const float*)d_in[2];
    const float* h2_0 = (const float*)d_in[3];
    const float* c2_0 = (const float*)d_in[4];
    const float* Wih1 = (const float*)d_in[5];
    const float* Whh1 = (const float*)d_in[6];
    const float* bih1 = (const float*)d_in[7];
    const float* bhh1 = (const float*)d_in[8];
    const float* Wih2 = (const float*)d_in[9];
    const float* Whh2 = (const float*)d_in[10];
    const float* bih2 = (const float*)d_in[11];
    const float* bhh2 = (const float*)d_in[12];
    const float* Wout = (const float*)d_in[13];
    const float* bout = (const float*)d_in[14];
    float* out = (float*)d_out;
    (void)in_sizes; (void)n_in; (void)out_size; (void)ws_size;

    uint8_t* ws = (uint8_t*)d_ws;
    size_t off = 0;
    auto alloc = [&](size_t bytes) { void* p = ws + off; off += (bytes + 255) & ~(size_t)255; return p; };
    __hip_bfloat16* A2_0  = (__hip_bfloat16*)alloc((size_t)B_SZ * 2048 * 2);
    __hip_bfloat16* A2_1  = (__hip_bfloat16*)alloc((size_t)B_SZ * 2048 * 2);
    float*          c1    = (float*)alloc((size_t)B_SZ * H_SZ * 4);
    float*          c2    = (float*)alloc((size_t)B_SZ * H_SZ * 4);
    __hip_bfloat16* Whh1p = (__hip_bfloat16*)alloc((size_t)G4 * H_SZ * 2);
    __hip_bfloat16* Wcat2p= (__hip_bfloat16*)alloc((size_t)G4 * 2048 * 2);
    float*          bias1p= (float*)alloc(G4 * 4);
    float*          bias2p= (float*)alloc(G4 * 4);
    float*          wih1p = (float*)alloc(G4 * 4);
    float*          xT    = (float*)alloc((size_t)T_SZ * B_SZ * 4);

    __hip_bfloat16* A2[2] = { A2_0, A2_1 };

    k_prep_w1<<<(G4 * H_SZ + 255) / 256, 256, 0, stream>>>(Whh1, Whh1p);
    k_prep_w2<<<(G4 * 2048 + 255) / 256, 256, 0, stream>>>(Wih2, Whh2, Wcat2p);
    k_prep_vec<<<(G4 + 255) / 256, 256, 0, stream>>>(bih1, bhh1, bih2, bhh2, Wih1,
                                                     bias1p, bias2p, wih1p);
    k_xT<<<(B_SZ * T_SZ + 255) / 256, 256, 0, stream>>>(x, xT);
    k_init_state<<<(B_SZ * H_SZ + 255) / 256, 256, 0, stream>>>(h1_0, c1_0, h2_0, c2_0,
                                                                A2_0, A2_1, c1, c2);

    const int gemm_blocks = (B_SZ / BM) * (G4 / BN);   // 512

    for (int t = 0; t < T_SZ; ++t) {
        __hip_bfloat16* Pprev = A2[(t + 1) & 1];   // P_{t-1}
        __hip_bfloat16* Pt    = A2[t & 1];         // P_t
        // layer 1: reads h1_{t-1} (Pprev first half), writes h1_t -> Pt first half
        k_gemm_cell<1><<<gemm_blocks, 512, 0, stream>>>(
            (const __hip_bfloat16*)Pprev, 2048, Whh1p, 1024, 1024,
            bias1p, wih1p, xT, t, c1, Pt);
        // layer 2: reads [h1_t | h2_{t-1}] = Pt, writes h2_t -> P_{t+1} second half
        k_gemm_cell<2><<<gemm_blocks, 512, 0, stream>>>(
            (const __hip_bfloat16*)Pt, 2048, Wcat2p, 2048, 2048,
            bias2p, nullptr, nullptr, 0, c2, A2[(t + 1) & 1] + 1024);
    }
    // final h2 is in P_24 = A2[0] second half (T=24 even)
    k_out<<<(B_SZ * 64 + 255) / 256, 256, 0, stream>>>(A2_0 + 1024, Wout, bout, out);
}